// Round 14
// baseline (732.451 us; speedup 1.0000x reference)
//
#include <hip/hip_runtime.h>
#include <stdint.h>
#include <math.h>

#define NTOK 4096
#define DIM  1024
#define NEXP 64
#define KSEL 6
#define FF   1408
#define FF2  2816
#define DFFC 4096
#define CAPE 768

typedef __bf16 bf16x8 __attribute__((ext_vector_type(8)));
typedef float  f32x4  __attribute__((ext_vector_type(4)));

__device__ __forceinline__ float bf2f(uint32_t h) {
  union { uint32_t u; float f; } v; v.u = h << 16; return v.f;
}
__device__ __forceinline__ uint16_t f2bf(float f) {
  union { float f; uint32_t u; } v; v.f = f;
  return (uint16_t)((v.u + 0x7fffu + ((v.u >> 16) & 1u)) >> 16);
}
// packed RNE f32->bf16 pair (low = a, high = b)
__device__ __forceinline__ uint32_t pk_bf16(float a, float b) {
  uint32_t r;
  asm("v_cvt_pk_bf16_f32 %0, %1, %2" : "=v"(r) : "v"(a), "v"(b));
  return r;
}
// LDS XOR swizzle in halves (bits 3-5), proven conflict-free in r3
__device__ __forceinline__ int swzh(int r) { return ((r ^ (r >> 2)) & 7) << 3; }

__device__ __forceinline__ void load_lds16(const void* g, void* l) {
  __builtin_amdgcn_global_load_lds((const __attribute__((address_space(1))) void*)g,
                                   (__attribute__((address_space(3))) void*)l, 16, 0, 0);
}

// ---------------- router: logits, top-6, gating, z partial, bf16 x ----------------
__global__ __launch_bounds__(256) void router_kernel(const float* __restrict__ x,
                                                     const float* __restrict__ rw,
                                                     int* __restrict__ topk,
                                                     uint16_t* __restrict__ gating,
                                                     float* __restrict__ tokz,
                                                     uint16_t* __restrict__ hb) {
  __shared__ float hs[16 * DIM];
  __shared__ float lg[16][NEXP];
  const int tid = threadIdx.x;
  const int t0 = blockIdx.x * 16;
  const float4* xin = (const float4*)(x + (size_t)t0 * DIM);
  float4* hs4 = (float4*)hs;
  for (int i = tid; i < 16 * DIM / 4; i += 256) hs4[i] = xin[i];
  __syncthreads();
  {
    ushort4* hbo = (ushort4*)(hb + (size_t)t0 * DIM);
    for (int i = tid; i < 16 * DIM / 4; i += 256) {
      float4 v = hs4[i];
      ushort4 o;
      o.x = f2bf(v.x); o.y = f2bf(v.y); o.z = f2bf(v.z); o.w = f2bf(v.w);
      hbo[i] = o;
    }
  }
  const int e = tid >> 2, q = tid & 3;
  float part[16];
#pragma unroll
  for (int tt = 0; tt < 16; tt++) part[tt] = 0.f;
  const float4* rw4 = (const float4*)(rw + (size_t)e * DIM + q * 256);
  for (int i = 0; i < 64; i++) {
    float4 w = rw4[i];
#pragma unroll
    for (int tt = 0; tt < 16; tt++) {
      float4 h = *(const float4*)(hs + tt * DIM + q * 256 + i * 4);
      part[tt] += h.x * w.x + h.y * w.y + h.z * w.z + h.w * w.w;
    }
  }
#pragma unroll
  for (int tt = 0; tt < 16; tt++) {
    float v = part[tt];
    v += __shfl_xor(v, 1);
    v += __shfl_xor(v, 2);
    if (q == 0) lg[tt][e] = v;
  }
  __syncthreads();
  const int wid = tid >> 6, lane = tid & 63;
  for (int ti = 0; ti < 4; ti++) {
    int tt = wid * 4 + ti;
    float v = lg[tt][lane];
    float z = v * v;
#pragma unroll
    for (int off = 32; off; off >>= 1) z += __shfl_xor(z, off);
    float bv[KSEL]; int bi[KSEL];
#pragma unroll
    for (int s = 0; s < KSEL; s++) {
      float m = v; int mi = lane;
#pragma unroll
      for (int off = 32; off; off >>= 1) {
        float om = __shfl_xor(m, off); int oi = __shfl_xor(mi, off);
        if (om > m || (om == m && oi < mi)) { m = om; mi = oi; }
      }
      bv[s] = m; bi[s] = mi;
      if (lane == mi) v = -3.0e38f;
    }
    if (lane == 0) {
      int t = t0 + tt;
      tokz[t] = z;
      float mx = bv[0];
      float ex[KSEL], sum = 0.f;
#pragma unroll
      for (int s = 0; s < KSEL; s++) { ex[s] = expf(bv[s] - mx); sum += ex[s]; }
      float inv = 1.f / sum;
#pragma unroll
      for (int s = 0; s < KSEL; s++) {
        topk[t * KSEL + s] = bi[s];
        gating[t * KSEL + s] = f2bf(ex[s] * inv);
      }
    }
  }
}

// ---------------- dispatch (blocks 0..63) + z_loss reduce (block 64) ----------------
__global__ __launch_bounds__(64) void dispatch_kernel(const int* __restrict__ topk,
                                                      int* __restrict__ dest,
                                                      int* __restrict__ invmap,
                                                      int* __restrict__ counts,
                                                      const float* __restrict__ tz,
                                                      float* __restrict__ zout) {
  const int lane = threadIdx.x;
  if (blockIdx.x == NEXP) {
    float a = 0.f;
    for (int i = lane; i < NTOK; i += 64) a += tz[i];
#pragma unroll
    for (int off = 32; off; off >>= 1) a += __shfl_xor(a, off);
    if (lane == 0) zout[0] = a * (1e-6f / ((float)NTOK * (float)NEXP));
    return;
  }
  const int e = blockIdx.x;
  int base = 0;
  for (int it = 0; it < (NTOK * KSEL) / 64; it++) {
    int p = it * 64 + lane;
    int ex = topk[p];
    bool m = (ex == e);
    unsigned long long mask = __ballot(m);
    if (m) {
      int intra = base + __popcll(mask & ((1ull << lane) - 1ull));
      if (intra < CAPE) {
        dest[p] = e * CAPE + intra;
        invmap[e * CAPE + intra] = p / KSEL;
      } else {
        dest[p] = -1;
      }
    }
    base += __popcll(mask);
  }
  if (lane == 0) counts[e] = base < CAPE ? base : CAPE;
}

// ---------------- GEMM body (r11/r13 structure + T5 setprio) ----------------
// A-dbuf gload_lds, T14 B reg-split, raw counted barriers, no vmem drains,
// 48 KiB LDS -> 3 blocks/CU. The 3 co-resident blocks are mutually unsynced,
// so a SIMD hosts waves at different phases -> setprio(1) around the MFMA
// cluster biases the scheduler toward the MFMA-phase wave (T5, m191 regime).
// EPI : 0 = store bf16, 1 = store f32, 2 = SwiGLU-pair store (interleaved-16) -> bf16
// BSRC: 1 = fp32 B^T [N,K] | 2 = fp32 B [K,N] (reg transpose; REMAP = w12 interleave)
//       3 = fp32 dual B^T gate/up interleaved per 16 virtual cols
// Split-K via the e-slot (strideA/strideB = K-offset, strideC = partial stride).
#define BM 128
#define BN 128
#define BKK 64

struct GArgs {
  const uint16_t* A; const float* B; const float* B2; void* C;
  const int* invmap; const int* counts;
  int K, lda, ldb, ldc;
  long long strideA, strideB, strideC;
  int grouped, nM, nN, nblk;
};

template<int EPI, int BSRC, bool IND, bool REMAP>
__device__ __forceinline__ void gemm_body(const GArgs& g, int bid,
                                          uint16_t* sAbase, uint16_t* sB) {
  // XCD-chunked decode: consecutive-on-XCD blocks share (e, n) and sweep m
  const int per = g.nblk >> 3;
  const int w = (bid & 7) * per + (bid >> 3);
  const int mi = w % g.nM;
  const int q1 = w / g.nM;
  const int ni = q1 % g.nN;
  const int e  = q1 / g.nN;
  int cnt = 1 << 30;
  if (g.grouped) {
    cnt = g.counts[e];
    if (mi * BM >= cnt) return;
  }
  const int bm0 = mi * BM, bn0 = ni * BN;
  const uint16_t* Ab = g.A + (size_t)e * g.strideA;
  const float* Bb = g.B + (size_t)e * g.strideB;
  const int tid = threadIdx.x, wid = tid >> 6, lane = tid & 63;
  const int lda = g.lda, ldb = g.ldb, ldc = g.ldc;

  // ---- A-side pointers (bf16, global_load_lds, source pre-swizzled) ----
  const int sa = tid >> 3;
  const int colk = (((tid & 7) ^ ((sa ^ (sa >> 2)) & 7)) * 8);
  const uint16_t* ap[4];
#pragma unroll
  for (int i = 0; i < 4; i++) {
    int row = i * 32 + sa;
    int ar = bm0 + row;
    if constexpr (IND) {
      int cr = ar < cnt ? ar : (cnt - 1);
      ar = g.invmap[e * CAPE + cr];
    }
    ap[i] = Ab + (size_t)ar * lda + colk;
  }

  // ---- B-side source pointers ----
  const float* bpa = nullptr;
  const float* bpb = nullptr;
  if constexpr (BSRC == 1) {
    const int kc = (tid & 15) * 4;
    bpa = Bb + (size_t)(bn0 + (tid >> 4)) * ldb + kc;
  } else if constexpr (BSRC == 3) {
    const int kc = (tid & 15) * 4;
    const int gcol = (bn0 >> 1) + (tid >> 4);
    bpa = g.B  + (size_t)gcol * ldb + kc;
    bpb = g.B2 + (size_t)gcol * ldb + kc;
  } else {
    const int n0 = 4 * (tid & 31);
    int vn0 = bn0 + n0;
    int ng0;
    if constexpr (REMAP) {
      int blk = vn0 >> 5, lo = vn0 & 31;
      ng0 = blk * 16 + (lo & 15) + (lo < 16 ? 0 : FF);
    } else {
      ng0 = vn0;
    }
    bpa = Bb + (size_t)(4 * (tid >> 5)) * ldb + ng0;
  }

  auto loadB = [&](f32x4 (&v)[8]) {
    if constexpr (BSRC == 1) {
#pragma unroll
      for (int it = 0; it < 8; it++)
        v[it] = *(const f32x4*)(bpa + (size_t)(it * 16) * ldb);
      bpa += BKK;
    } else if constexpr (BSRC == 3) {
#pragma unroll
      for (int it = 0; it < 8; it++) {
        const float* s = (it & 1) ? bpb : bpa;
        v[it] = *(const f32x4*)(s + (size_t)((it >> 1) * 16) * ldb);
      }
      bpa += BKK; bpb += BKK;
    } else {
#pragma unroll
      for (int i2 = 0; i2 < 2; i2++)
#pragma unroll
        for (int j = 0; j < 4; j++)
          v[i2 * 4 + j] = *(const f32x4*)(bpa + (size_t)(32 * i2 + j) * ldb);
      bpa += (size_t)BKK * ldb;
    }
  };
  auto issueA = [&](int buf) {
#pragma unroll
    for (int i = 0; i < 4; i++) {
      load_lds16(ap[i], sAbase + buf * (BM * BKK) + i * 2048 + wid * 512);
      ap[i] += BKK;
    }
  };
  auto writeB = [&](f32x4 (&v)[8]) {
    if constexpr (BSRC == 1 || BSRC == 3) {
      const int kc = (tid & 15) * 4;
#pragma unroll
      for (int it = 0; it < 8; it++) {
        int nr = (tid >> 4) + it * 16;
        uint2 p;
        p.x = pk_bf16(v[it][0], v[it][1]);
        p.y = pk_bf16(v[it][2], v[it][3]);
        *(uint2*)(sB + nr * BKK + (kc ^ swzh(nr))) = p;
      }
    } else {
      const int n0 = 4 * (tid & 31);
#pragma unroll
      for (int i2 = 0; i2 < 2; i2++) {
        int kk0 = 4 * (tid >> 5) + 32 * i2;
#pragma unroll
        for (int c = 0; c < 4; c++) {
          int nr = n0 + c;
          uint2 p;
          p.x = pk_bf16(v[i2 * 4 + 0][c], v[i2 * 4 + 1][c]);
          p.y = pk_bf16(v[i2 * 4 + 2][c], v[i2 * 4 + 3][c]);
          *(uint2*)(sB + nr * BKK + (kk0 ^ swzh(nr))) = p;
        }
      }
    }
  };

  f32x4 zero = {0.f, 0.f, 0.f, 0.f};
  f32x4 acc[4][4];
#pragma unroll
  for (int i = 0; i < 4; i++)
#pragma unroll
    for (int j = 0; j < 4; j++) acc[i][j] = zero;
  const int wm = wid >> 1, wn = wid & 1;

  f32x4 bv[8];
  // prologue: A(0) DMA + B(0) regs (only place full latency is exposed)
  issueA(0);
  loadB(bv);

  const int T = g.K / BKK;
  for (int t = 0; t < T; t++) {
    const int cur = t & 1, nb = cur ^ 1;
    const bool more = (t + 1 < T);
    if (more) issueA(nb);    // A(t+1) DMA: full iter to land
    writeB(bv);              // auto vmcnt wait: drains B(t) regs + older A(t) DMAs
    if (more) loadB(bv);     // B(t+1): full iter of cover
    asm volatile("s_waitcnt lgkmcnt(0)" ::: "memory");
    __builtin_amdgcn_sched_barrier(0);
    __builtin_amdgcn_s_barrier();
    __builtin_amdgcn_sched_barrier(0);
    __builtin_amdgcn_s_setprio(1);
    // MFMA on sA[cur] + sB
#pragma unroll
    for (int ks = 0; ks < 2; ks++) {
      const int kb = ks * 32 + (lane >> 4) * 8;
      bf16x8 af[4], bfr[4];
#pragma unroll
      for (int f = 0; f < 4; f++) {
        int rowA = wm * 64 + f * 16 + (lane & 15);
        af[f] = *(const bf16x8*)(sAbase + cur * (BM * BKK) + rowA * BKK + (kb ^ swzh(rowA)));
      }
#pragma unroll
      for (int f = 0; f < 4; f++) {
        int rowB = wn * 64 + f * 16 + (lane & 15);
        bfr[f] = *(const bf16x8*)(sB + rowB * BKK + (kb ^ swzh(rowB)));
      }
#pragma unroll
      for (int fm = 0; fm < 4; fm++)
#pragma unroll
        for (int fn = 0; fn < 4; fn++)
          acc[fm][fn] = __builtin_amdgcn_mfma_f32_16x16x32_bf16(af[fm], bfr[fn],
                                                                acc[fm][fn], 0, 0, 0);
    }
    __builtin_amdgcn_s_setprio(0);
    __builtin_amdgcn_sched_barrier(0);
    __builtin_amdgcn_s_barrier();
    __builtin_amdgcn_sched_barrier(0);
  }

  const int lr = (lane >> 4) * 4, lc = lane & 15;
  if constexpr (EPI == 2) {
    uint16_t* outp = (uint16_t*)g.C + (size_t)e * g.strideC;
#pragma unroll
    for (int fm = 0; fm < 4; fm++) {
#pragma unroll
      for (int fp = 0; fp < 2; fp++) {
        f32x4 gg = acc[fm][2 * fp], u = acc[fm][2 * fp + 1];
        int fcol = (bn0 >> 1) + wn * 32 + fp * 16 + lc;
#pragma unroll
        for (int j = 0; j < 4; j++) {
          int r = bm0 + wm * 64 + fm * 16 + lr + j;
          float gv = gg[j];
          float sv = (gv / (1.f + expf(-gv))) * u[j];
          outp[(size_t)r * ldc + fcol] = f2bf(sv);
        }
      }
    }
  } else if constexpr (EPI == 1) {
    float* outp = (float*)g.C + (size_t)e * g.strideC;
#pragma unroll
    for (int fm = 0; fm < 4; fm++)
#pragma unroll
      for (int fn = 0; fn < 4; fn++) {
        int col = bn0 + wn * 64 + fn * 16 + lc;
#pragma unroll
        for (int j = 0; j < 4; j++) {
          int r = bm0 + wm * 64 + fm * 16 + lr + j;
          outp[(size_t)r * ldc + col] = acc[fm][fn][j];
        }
      }
  } else {
    uint16_t* outp = (uint16_t*)g.C + (size_t)e * g.strideC;
#pragma unroll
    for (int fm = 0; fm < 4; fm++)
#pragma unroll
      for (int fn = 0; fn < 4; fn++) {
        int col = bn0 + wn * 64 + fn * 16 + lc;
#pragma unroll
        for (int j = 0; j < 4; j++) {
          int r = bm0 + wm * 64 + fm * 16 + lr + j;
          outp[(size_t)r * ldc + col] = f2bf(acc[fm][fn][j]);
        }
      }
  }
}

// ---------------- fused launches: independent GEMM pairs share one grid ----------
__global__ __launch_bounds__(256, 3) void fused_up(GArgs a, GArgs b) {
  __shared__ alignas(16) uint16_t sA[2][BM * BKK];
  __shared__ alignas(16) uint16_t sB[BN * BKK];
  const int bid = blockIdx.x;
  if (bid < a.nblk) gemm_body<2, 3, false, false>(a, bid, &sA[0][0], sB);
  else              gemm_body<2, 2, true,  true >(b, bid - a.nblk, &sA[0][0], sB);
}
__global__ __launch_bounds__(256, 3) void fused_down(GArgs a, GArgs b) {
  __shared__ alignas(16) uint16_t sA[2][BM * BKK];
  __shared__ alignas(16) uint16_t sB[BN * BKK];
  const int bid = blockIdx.x;
  if (bid < a.nblk) gemm_body<1, 1, false, false>(a, bid, &sA[0][0], sB);
  else              gemm_body<0, 2, false, false>(b, bid - a.nblk, &sA[0][0], sB);
}

// ---------------- combine (sums 2 split-K down partials) ----------------
__global__ __launch_bounds__(256) void combine_kernel(const float* __restrict__ shout,
                                                      const uint16_t* __restrict__ eout,
                                                      const int* __restrict__ dest,
                                                      const uint16_t* __restrict__ gating,
                                                      float* __restrict__ out) {
  const int t = blockIdx.x;
  const int d0 = threadIdx.x * 4;
  float4 s0 = *(const float4*)(shout + (size_t)t * DIM + d0);
  float4 s1 = *(const float4*)(shout + (size_t)NTOK * DIM + (size_t)t * DIM + d0);
  float rx = 0.f, ry = 0.f, rz = 0.f, rw = 0.f;
#pragma unroll
  for (int k = 0; k < KSEL; k++) {
    int dp = dest[t * KSEL + k];
    if (dp >= 0) {
      float gw = bf2f(gating[t * KSEL + k]);
      ushort4 ev = *(const ushort4*)(eout + (size_t)dp * DIM + d0);
      rx += gw * bf2f(ev.x);
      ry += gw * bf2f(ev.y);
      rz += gw * bf2f(ev.z);
      rw += gw * bf2f(ev.w);
    }
  }
  float4 o;
  o.x = (s0.x + s1.x + rx) * 0.5f;
  o.y = (s0.y + s1.y + ry) * 0.5f;
  o.z = (s0.z + s1.z + rz) * 0.5f;
  o.w = (s0.w + s1.w + rw) * 0.5f;
  *(float4*)(out + (size_t)t * DIM + d0) = o;
}

extern "C" void kernel_launch(void* const* d_in, const int* in_sizes, int n_in,
                              void* d_out, int out_size, void* d_ws, size_t ws_size,
                              hipStream_t stream) {
  (void)in_sizes; (void)n_in; (void)out_size; (void)ws_size;
  const float* x   = (const float*)d_in[0];
  const float* rw  = (const float*)d_in[1];
  const float* w12 = (const float*)d_in[2];
  const float* w3  = (const float*)d_in[3];
  const float* gw  = (const float*)d_in[4];
  const float* uw  = (const float*)d_in[5];
  const float* dw  = (const float*)d_in[6];
  float* out = (float*)d_out;

  char* ws = (char*)d_ws;
  size_t off = 0;
  auto alloc = [&](size_t sz) -> void* {
    void* p = ws + off;
    off += (sz + 255) & ~(size_t)255;
    return p;
  };
  uint16_t* HB    = (uint16_t*)alloc((size_t)NTOK * DIM * 2);
  uint16_t* S1    = (uint16_t*)alloc((size_t)NTOK * DFFC * 2);
  uint16_t* ACT   = (uint16_t*)alloc((size_t)NEXP * CAPE * FF * 2);
  uint16_t* EOUT  = (uint16_t*)alloc((size_t)NEXP * CAPE * DIM * 2);
  float* SHOUT    = (float*)alloc((size_t)2 * NTOK * DIM * 4);  // 2 split-K partials
  int* TOPKB      = (int*)alloc((size_t)NTOK * KSEL * 4);
  uint16_t* GATING= (uint16_t*)alloc((size_t)NTOK * KSEL * 2);
  int* DEST       = (int*)alloc((size_t)NTOK * KSEL * 4);
  int* INVMAP     = (int*)alloc((size_t)NEXP * CAPE * 4);
  int* COUNTS     = (int*)alloc((size_t)NEXP * 4);
  float* TOKZ     = (float*)alloc((size_t)NTOK * 4);

  // router, then dispatch (+fused z-loss reduce in block NEXP)
  router_kernel<<<NTOK / 16, 256, 0, stream>>>(x, rw, TOPKB, GATING, TOKZ, HB);
  dispatch_kernel<<<NEXP + 1, 64, 0, stream>>>(TOPKB, DEST, INVMAP, COUNTS,
                                               TOKZ, out + (size_t)NTOK * DIM);

  // fused launch 1: gate+up SwiGLU (dense) + w12 grouped SwiGLU
  GArgs gup = { HB, gw, uw, S1, nullptr, nullptr,
                DIM, DIM, DIM, DFFC, 0, 0, 0,
                0, NTOK / BM, 2 * DFFC / BN, (NTOK / BM) * (2 * DFFC / BN) };
  GArgs g12 = { HB, w12, nullptr, ACT, INVMAP, COUNTS,
                DIM, DIM, FF2, FF, 0, (long long)DIM * FF2, (long long)CAPE * FF,
                1, CAPE / BM, FF2 / BN, (CAPE / BM) * (FF2 / BN) * NEXP };
  fused_up<<<gup.nblk + g12.nblk, 256, 0, stream>>>(gup, g12);

  // fused launch 2: down-proj (split-K=2, dense) + w3 grouped
  GArgs gdn = { S1, dw, nullptr, SHOUT, nullptr, nullptr,
                DFFC / 2, DFFC, DFFC, DIM, DFFC / 2, DFFC / 2, (long long)NTOK * DIM,
                0, NTOK / BM, DIM / BN, (NTOK / BM) * (DIM / BN) * 2 };
  GArgs gw3 = { ACT, w3, nullptr, EOUT, nullptr, COUNTS,
                FF, FF, DIM, DIM, (long long)CAPE * FF, (long long)FF * DIM,
                (long long)CAPE * DIM, 1, CAPE / BM, DIM / BN,
                (CAPE / BM) * (DIM / BN) * NEXP };
  fused_down<<<gdn.nblk + gw3.nblk, 256, 0, stream>>>(gdn, gw3);

  // combine
  combine_kernel<<<NTOK, 256, 0, stream>>>(SHOUT, EOUT, DEST, GATING, out);
}

// Round 15
// 730.209 us; speedup vs baseline: 1.0031x; 1.0031x over previous
//
#include <hip/hip_runtime.h>
#include <stdint.h>
#include <math.h>

#define NTOK 4096
#define DIM  1024
#define NEXP 64
#define KSEL 6
#define FF   1408
#define FF2  2816
#define DFFC 4096
#define CAPE 768

typedef __bf16 bf16x8 __attribute__((ext_vector_type(8)));
typedef float  f32x4  __attribute__((ext_vector_type(4)));

__device__ __forceinline__ float bf2f(uint32_t h) {
  union { uint32_t u; float f; } v; v.u = h << 16; return v.f;
}
__device__ __forceinline__ uint16_t f2bf(float f) {
  union { float f; uint32_t u; } v; v.f = f;
  return (uint16_t)((v.u + 0x7fffu + ((v.u >> 16) & 1u)) >> 16);
}
// packed RNE f32->bf16 pair (low = a, high = b)
__device__ __forceinline__ uint32_t pk_bf16(float a, float b) {
  uint32_t r;
  asm("v_cvt_pk_bf16_f32 %0, %1, %2" : "=v"(r) : "v"(a), "v"(b));
  return r;
}
// LDS XOR swizzle in halves (bits 3-5), proven conflict-free in r3
__device__ __forceinline__ int swzh(int r) { return ((r ^ (r >> 2)) & 7) << 3; }

__device__ __forceinline__ void load_lds16(const void* g, void* l) {
  __builtin_amdgcn_global_load_lds((const __attribute__((address_space(1))) void*)g,
                                   (__attribute__((address_space(3))) void*)l, 16, 0, 0);
}

// ---------------- router: logits, top-6, gating, z partial, bf16 x ----------------
__global__ __launch_bounds__(256) void router_kernel(const float* __restrict__ x,
                                                     const float* __restrict__ rw,
                                                     int* __restrict__ topk,
                                                     uint16_t* __restrict__ gating,
                                                     float* __restrict__ tokz,
                                                     uint16_t* __restrict__ hb) {
  __shared__ float hs[16 * DIM];
  __shared__ float lg[16][NEXP];
  const int tid = threadIdx.x;
  const int t0 = blockIdx.x * 16;
  const float4* xin = (const float4*)(x + (size_t)t0 * DIM);
  float4* hs4 = (float4*)hs;
  for (int i = tid; i < 16 * DIM / 4; i += 256) hs4[i] = xin[i];
  __syncthreads();
  {
    ushort4* hbo = (ushort4*)(hb + (size_t)t0 * DIM);
    for (int i = tid; i < 16 * DIM / 4; i += 256) {
      float4 v = hs4[i];
      ushort4 o;
      o.x = f2bf(v.x); o.y = f2bf(v.y); o.z = f2bf(v.z); o.w = f2bf(v.w);
      hbo[i] = o;
    }
  }
  const int e = tid >> 2, q = tid & 3;
  float part[16];
#pragma unroll
  for (int tt = 0; tt < 16; tt++) part[tt] = 0.f;
  const float4* rw4 = (const float4*)(rw + (size_t)e * DIM + q * 256);
  for (int i = 0; i < 64; i++) {
    float4 w = rw4[i];
#pragma unroll
    for (int tt = 0; tt < 16; tt++) {
      float4 h = *(const float4*)(hs + tt * DIM + q * 256 + i * 4);
      part[tt] += h.x * w.x + h.y * w.y + h.z * w.z + h.w * w.w;
    }
  }
#pragma unroll
  for (int tt = 0; tt < 16; tt++) {
    float v = part[tt];
    v += __shfl_xor(v, 1);
    v += __shfl_xor(v, 2);
    if (q == 0) lg[tt][e] = v;
  }
  __syncthreads();
  const int wid = tid >> 6, lane = tid & 63;
  for (int ti = 0; ti < 4; ti++) {
    int tt = wid * 4 + ti;
    float v = lg[tt][lane];
    float z = v * v;
#pragma unroll
    for (int off = 32; off; off >>= 1) z += __shfl_xor(z, off);
    float bv[KSEL]; int bi[KSEL];
#pragma unroll
    for (int s = 0; s < KSEL; s++) {
      float m = v; int mi = lane;
#pragma unroll
      for (int off = 32; off; off >>= 1) {
        float om = __shfl_xor(m, off); int oi = __shfl_xor(mi, off);
        if (om > m || (om == m && oi < mi)) { m = om; mi = oi; }
      }
      bv[s] = m; bi[s] = mi;
      if (lane == mi) v = -3.0e38f;
    }
    if (lane == 0) {
      int t = t0 + tt;
      tokz[t] = z;
      float mx = bv[0];
      float ex[KSEL], sum = 0.f;
#pragma unroll
      for (int s = 0; s < KSEL; s++) { ex[s] = expf(bv[s] - mx); sum += ex[s]; }
      float inv = 1.f / sum;
#pragma unroll
      for (int s = 0; s < KSEL; s++) {
        topk[t * KSEL + s] = bi[s];
        gating[t * KSEL + s] = f2bf(ex[s] * inv);
      }
    }
  }
}

// ---------------- dispatch (blocks 0..63) + z_loss reduce (block 64) ----------------
__global__ __launch_bounds__(64) void dispatch_kernel(const int* __restrict__ topk,
                                                      int* __restrict__ dest,
                                                      int* __restrict__ invmap,
                                                      int* __restrict__ counts,
                                                      const float* __restrict__ tz,
                                                      float* __restrict__ zout) {
  const int lane = threadIdx.x;
  if (blockIdx.x == NEXP) {
    float a = 0.f;
    for (int i = lane; i < NTOK; i += 64) a += tz[i];
#pragma unroll
    for (int off = 32; off; off >>= 1) a += __shfl_xor(a, off);
    if (lane == 0) zout[0] = a * (1e-6f / ((float)NTOK * (float)NEXP));
    return;
  }
  const int e = blockIdx.x;
  int base = 0;
  for (int it = 0; it < (NTOK * KSEL) / 64; it++) {
    int p = it * 64 + lane;
    int ex = topk[p];
    bool m = (ex == e);
    unsigned long long mask = __ballot(m);
    if (m) {
      int intra = base + __popcll(mask & ((1ull << lane) - 1ull));
      if (intra < CAPE) {
        dest[p] = e * CAPE + intra;
        invmap[e * CAPE + intra] = p / KSEL;
      } else {
        dest[p] = -1;
      }
    }
    base += __popcll(mask);
  }
  if (lane == 0) counts[e] = base < CAPE ? base : CAPE;
}

// ---------------- GEMM body (r11/r13 structure, measured best 731.9 us) ----------------
// A-dbuf gload_lds, T14 B reg-split, raw counted barriers, no vmem drains,
// 48 KiB LDS -> 3 blocks/CU.
//   iter t: issueA(t+1 -> sA[nb]); writeB(t) [auto vmcnt drains bv(t)+A(t)];
//           loadB(t+1); lgkmcnt(0); s_barrier; MFMA(sA[cur],sB); s_barrier.
// EPI : 0 = store bf16, 1 = store f32, 2 = SwiGLU-pair store (interleaved-16) -> bf16
// BSRC: 1 = fp32 B^T [N,K] | 2 = fp32 B [K,N] (reg transpose; REMAP = w12 interleave)
//       3 = fp32 dual B^T gate/up interleaved per 16 virtual cols
// Split-K via the e-slot (strideA/strideB = K-offset, strideC = partial stride).
#define BM 128
#define BN 128
#define BKK 64

struct GArgs {
  const uint16_t* A; const float* B; const float* B2; void* C;
  const int* invmap; const int* counts;
  int K, lda, ldb, ldc;
  long long strideA, strideB, strideC;
  int grouped, nM, nN, nblk;
};

template<int EPI, int BSRC, bool IND, bool REMAP>
__device__ __forceinline__ void gemm_body(const GArgs& g, int bid,
                                          uint16_t* sAbase, uint16_t* sB) {
  // XCD-chunked decode: consecutive-on-XCD blocks share (e, n) and sweep m
  const int per = g.nblk >> 3;
  const int w = (bid & 7) * per + (bid >> 3);
  const int mi = w % g.nM;
  const int q1 = w / g.nM;
  const int ni = q1 % g.nN;
  const int e  = q1 / g.nN;
  int cnt = 1 << 30;
  if (g.grouped) {
    cnt = g.counts[e];
    if (mi * BM >= cnt) return;
  }
  const int bm0 = mi * BM, bn0 = ni * BN;
  const uint16_t* Ab = g.A + (size_t)e * g.strideA;
  const float* Bb = g.B + (size_t)e * g.strideB;
  const int tid = threadIdx.x, wid = tid >> 6, lane = tid & 63;
  const int lda = g.lda, ldb = g.ldb, ldc = g.ldc;

  // ---- A-side pointers (bf16, global_load_lds, source pre-swizzled) ----
  const int sa = tid >> 3;
  const int colk = (((tid & 7) ^ ((sa ^ (sa >> 2)) & 7)) * 8);
  const uint16_t* ap[4];
#pragma unroll
  for (int i = 0; i < 4; i++) {
    int row = i * 32 + sa;
    int ar = bm0 + row;
    if constexpr (IND) {
      int cr = ar < cnt ? ar : (cnt - 1);
      ar = g.invmap[e * CAPE + cr];
    }
    ap[i] = Ab + (size_t)ar * lda + colk;
  }

  // ---- B-side source pointers ----
  const float* bpa = nullptr;
  const float* bpb = nullptr;
  if constexpr (BSRC == 1) {
    const int kc = (tid & 15) * 4;
    bpa = Bb + (size_t)(bn0 + (tid >> 4)) * ldb + kc;
  } else if constexpr (BSRC == 3) {
    const int kc = (tid & 15) * 4;
    const int gcol = (bn0 >> 1) + (tid >> 4);
    bpa = g.B  + (size_t)gcol * ldb + kc;
    bpb = g.B2 + (size_t)gcol * ldb + kc;
  } else {
    const int n0 = 4 * (tid & 31);
    int vn0 = bn0 + n0;
    int ng0;
    if constexpr (REMAP) {
      int blk = vn0 >> 5, lo = vn0 & 31;
      ng0 = blk * 16 + (lo & 15) + (lo < 16 ? 0 : FF);
    } else {
      ng0 = vn0;
    }
    bpa = Bb + (size_t)(4 * (tid >> 5)) * ldb + ng0;
  }

  auto loadB = [&](f32x4 (&v)[8]) {
    if constexpr (BSRC == 1) {
#pragma unroll
      for (int it = 0; it < 8; it++)
        v[it] = *(const f32x4*)(bpa + (size_t)(it * 16) * ldb);
      bpa += BKK;
    } else if constexpr (BSRC == 3) {
#pragma unroll
      for (int it = 0; it < 8; it++) {
        const float* s = (it & 1) ? bpb : bpa;
        v[it] = *(const f32x4*)(s + (size_t)((it >> 1) * 16) * ldb);
      }
      bpa += BKK; bpb += BKK;
    } else {
#pragma unroll
      for (int i2 = 0; i2 < 2; i2++)
#pragma unroll
        for (int j = 0; j < 4; j++)
          v[i2 * 4 + j] = *(const f32x4*)(bpa + (size_t)(32 * i2 + j) * ldb);
      bpa += (size_t)BKK * ldb;
    }
  };
  auto issueA = [&](int buf) {
#pragma unroll
    for (int i = 0; i < 4; i++) {
      load_lds16(ap[i], sAbase + buf * (BM * BKK) + i * 2048 + wid * 512);
      ap[i] += BKK;
    }
  };
  auto writeB = [&](f32x4 (&v)[8]) {
    if constexpr (BSRC == 1 || BSRC == 3) {
      const int kc = (tid & 15) * 4;
#pragma unroll
      for (int it = 0; it < 8; it++) {
        int nr = (tid >> 4) + it * 16;
        uint2 p;
        p.x = pk_bf16(v[it][0], v[it][1]);
        p.y = pk_bf16(v[it][2], v[it][3]);
        *(uint2*)(sB + nr * BKK + (kc ^ swzh(nr))) = p;
      }
    } else {
      const int n0 = 4 * (tid & 31);
#pragma unroll
      for (int i2 = 0; i2 < 2; i2++) {
        int kk0 = 4 * (tid >> 5) + 32 * i2;
#pragma unroll
        for (int c = 0; c < 4; c++) {
          int nr = n0 + c;
          uint2 p;
          p.x = pk_bf16(v[i2 * 4 + 0][c], v[i2 * 4 + 1][c]);
          p.y = pk_bf16(v[i2 * 4 + 2][c], v[i2 * 4 + 3][c]);
          *(uint2*)(sB + nr * BKK + (kk0 ^ swzh(nr))) = p;
        }
      }
    }
  };

  f32x4 zero = {0.f, 0.f, 0.f, 0.f};
  f32x4 acc[4][4];
#pragma unroll
  for (int i = 0; i < 4; i++)
#pragma unroll
    for (int j = 0; j < 4; j++) acc[i][j] = zero;
  const int wm = wid >> 1, wn = wid & 1;

  f32x4 bv[8];
  // prologue: A(0) DMA + B(0) regs (only place full latency is exposed)
  issueA(0);
  loadB(bv);

  const int T = g.K / BKK;
  for (int t = 0; t < T; t++) {
    const int cur = t & 1, nb = cur ^ 1;
    const bool more = (t + 1 < T);
    if (more) issueA(nb);    // A(t+1) DMA: full iter to land
    writeB(bv);              // auto vmcnt wait: drains B(t) regs + older A(t) DMAs
    if (more) loadB(bv);     // B(t+1): full iter of cover
    asm volatile("s_waitcnt lgkmcnt(0)" ::: "memory");
    __builtin_amdgcn_sched_barrier(0);
    __builtin_amdgcn_s_barrier();
    __builtin_amdgcn_sched_barrier(0);
    // MFMA on sA[cur] + sB
#pragma unroll
    for (int ks = 0; ks < 2; ks++) {
      const int kb = ks * 32 + (lane >> 4) * 8;
      bf16x8 af[4], bfr[4];
#pragma unroll
      for (int f = 0; f < 4; f++) {
        int rowA = wm * 64 + f * 16 + (lane & 15);
        af[f] = *(const bf16x8*)(sAbase + cur * (BM * BKK) + rowA * BKK + (kb ^ swzh(rowA)));
      }
#pragma unroll
      for (int f = 0; f < 4; f++) {
        int rowB = wn * 64 + f * 16 + (lane & 15);
        bfr[f] = *(const bf16x8*)(sB + rowB * BKK + (kb ^ swzh(rowB)));
      }
#pragma unroll
      for (int fm = 0; fm < 4; fm++)
#pragma unroll
        for (int fn = 0; fn < 4; fn++)
          acc[fm][fn] = __builtin_amdgcn_mfma_f32_16x16x32_bf16(af[fm], bfr[fn],
                                                                acc[fm][fn], 0, 0, 0);
    }
    __builtin_amdgcn_sched_barrier(0);
    __builtin_amdgcn_s_barrier();
    __builtin_amdgcn_sched_barrier(0);
  }

  const int lr = (lane >> 4) * 4, lc = lane & 15;
  if constexpr (EPI == 2) {
    uint16_t* outp = (uint16_t*)g.C + (size_t)e * g.strideC;
#pragma unroll
    for (int fm = 0; fm < 4; fm++) {
#pragma unroll
      for (int fp = 0; fp < 2; fp++) {
        f32x4 gg = acc[fm][2 * fp], u = acc[fm][2 * fp + 1];
        int fcol = (bn0 >> 1) + wn * 32 + fp * 16 + lc;
#pragma unroll
        for (int j = 0; j < 4; j++) {
          int r = bm0 + wm * 64 + fm * 16 + lr + j;
          float gv = gg[j];
          float sv = (gv / (1.f + expf(-gv))) * u[j];
          outp[(size_t)r * ldc + fcol] = f2bf(sv);
        }
      }
    }
  } else if constexpr (EPI == 1) {
    float* outp = (float*)g.C + (size_t)e * g.strideC;
#pragma unroll
    for (int fm = 0; fm < 4; fm++)
#pragma unroll
      for (int fn = 0; fn < 4; fn++) {
        int col = bn0 + wn * 64 + fn * 16 + lc;
#pragma unroll
        for (int j = 0; j < 4; j++) {
          int r = bm0 + wm * 64 + fm * 16 + lr + j;
          outp[(size_t)r * ldc + col] = acc[fm][fn][j];
        }
      }
  } else {
    uint16_t* outp = (uint16_t*)g.C + (size_t)e * g.strideC;
#pragma unroll
    for (int fm = 0; fm < 4; fm++)
#pragma unroll
      for (int fn = 0; fn < 4; fn++) {
        int col = bn0 + wn * 64 + fn * 16 + lc;
#pragma unroll
        for (int j = 0; j < 4; j++) {
          int r = bm0 + wm * 64 + fm * 16 + lr + j;
          outp[(size_t)r * ldc + col] = f2bf(acc[fm][fn][j]);
        }
      }
  }
}

// ---------------- fused launches: independent GEMM pairs share one grid ----------
__global__ __launch_bounds__(256, 3) void fused_up(GArgs a, GArgs b) {
  __shared__ alignas(16) uint16_t sA[2][BM * BKK];
  __shared__ alignas(16) uint16_t sB[BN * BKK];
  const int bid = blockIdx.x;
  if (bid < a.nblk) gemm_body<2, 3, false, false>(a, bid, &sA[0][0], sB);
  else              gemm_body<2, 2, true,  true >(b, bid - a.nblk, &sA[0][0], sB);
}
__global__ __launch_bounds__(256, 3) void fused_down(GArgs a, GArgs b) {
  __shared__ alignas(16) uint16_t sA[2][BM * BKK];
  __shared__ alignas(16) uint16_t sB[BN * BKK];
  const int bid = blockIdx.x;
  if (bid < a.nblk) gemm_body<1, 1, false, false>(a, bid, &sA[0][0], sB);
  else              gemm_body<0, 2, false, false>(b, bid - a.nblk, &sA[0][0], sB);
}

// ---------------- combine (sums 2 split-K down partials) ----------------
__global__ __launch_bounds__(256) void combine_kernel(const float* __restrict__ shout,
                                                      const uint16_t* __restrict__ eout,
                                                      const int* __restrict__ dest,
                                                      const uint16_t* __restrict__ gating,
                                                      float* __restrict__ out) {
  const int t = blockIdx.x;
  const int d0 = threadIdx.x * 4;
  float4 s0 = *(const float4*)(shout + (size_t)t * DIM + d0);
  float4 s1 = *(const float4*)(shout + (size_t)NTOK * DIM + (size_t)t * DIM + d0);
  float rx = 0.f, ry = 0.f, rz = 0.f, rw = 0.f;
#pragma unroll
  for (int k = 0; k < KSEL; k++) {
    int dp = dest[t * KSEL + k];
    if (dp >= 0) {
      float gw = bf2f(gating[t * KSEL + k]);
      ushort4 ev = *(const ushort4*)(eout + (size_t)dp * DIM + d0);
      rx += gw * bf2f(ev.x);
      ry += gw * bf2f(ev.y);
      rz += gw * bf2f(ev.z);
      rw += gw * bf2f(ev.w);
    }
  }
  float4 o;
  o.x = (s0.x + s1.x + rx) * 0.5f;
  o.y = (s0.y + s1.y + ry) * 0.5f;
  o.z = (s0.z + s1.z + rz) * 0.5f;
  o.w = (s0.w + s1.w + rw) * 0.5f;
  *(float4*)(out + (size_t)t * DIM + d0) = o;
}

extern "C" void kernel_launch(void* const* d_in, const int* in_sizes, int n_in,
                              void* d_out, int out_size, void* d_ws, size_t ws_size,
                              hipStream_t stream) {
  (void)in_sizes; (void)n_in; (void)out_size; (void)ws_size;
  const float* x   = (const float*)d_in[0];
  const float* rw  = (const float*)d_in[1];
  const float* w12 = (const float*)d_in[2];
  const float* w3  = (const float*)d_in[3];
  const float* gw  = (const float*)d_in[4];
  const float* uw  = (const float*)d_in[5];
  const float* dw  = (const float*)d_in[6];
  float* out = (float*)d_out;

  char* ws = (char*)d_ws;
  size_t off = 0;
  auto alloc = [&](size_t sz) -> void* {
    void* p = ws + off;
    off += (sz + 255) & ~(size_t)255;
    return p;
  };
  uint16_t* HB    = (uint16_t*)alloc((size_t)NTOK * DIM * 2);
  uint16_t* S1    = (uint16_t*)alloc((size_t)NTOK * DFFC * 2);
  uint16_t* ACT   = (uint16_t*)alloc((size_t)NEXP * CAPE * FF * 2);
  uint16_t* EOUT  = (uint16_t*)alloc((size_t)NEXP * CAPE * DIM * 2);
  float* SHOUT    = (float*)alloc((size_t)2 * NTOK * DIM * 4);  // 2 split-K partials
  int* TOPKB      = (int*)alloc((size_t)NTOK * KSEL * 4);
  uint16_t* GATING= (uint16_t*)alloc((size_t)NTOK * KSEL * 2);
  int* DEST       = (int*)alloc((size_t)NTOK * KSEL * 4);
  int* INVMAP     = (int*)alloc((size_t)NEXP * CAPE * 4);
  int* COUNTS     = (int*)alloc((size_t)NEXP * 4);
  float* TOKZ     = (float*)alloc((size_t)NTOK * 4);

  // router, then dispatch (+fused z-loss reduce in block NEXP)
  router_kernel<<<NTOK / 16, 256, 0, stream>>>(x, rw, TOPKB, GATING, TOKZ, HB);
  dispatch_kernel<<<NEXP + 1, 64, 0, stream>>>(TOPKB, DEST, INVMAP, COUNTS,
                                               TOKZ, out + (size_t)NTOK * DIM);

  // fused launch 1: gate+up SwiGLU (dense) + w12 grouped SwiGLU
  GArgs gup = { HB, gw, uw, S1, nullptr, nullptr,
                DIM, DIM, DIM, DFFC, 0, 0, 0,
                0, NTOK / BM, 2 * DFFC / BN, (NTOK / BM) * (2 * DFFC / BN) };
  GArgs g12 = { HB, w12, nullptr, ACT, INVMAP, COUNTS,
                DIM, DIM, FF2, FF, 0, (long long)DIM * FF2, (long long)CAPE * FF,
                1, CAPE / BM, FF2 / BN, (CAPE / BM) * (FF2 / BN) * NEXP };
  fused_up<<<gup.nblk + g12.nblk, 256, 0, stream>>>(gup, g12);

  // fused launch 2: down-proj (split-K=2, dense) + w3 grouped
  GArgs gdn = { S1, dw, nullptr, SHOUT, nullptr, nullptr,
                DFFC / 2, DFFC, DFFC, DIM, DFFC / 2, DFFC / 2, (long long)NTOK * DIM,
                0, NTOK / BM, DIM / BN, (NTOK / BM) * (DIM / BN) * 2 };
  GArgs gw3 = { ACT, w3, nullptr, EOUT, nullptr, COUNTS,
                FF, FF, DIM, DIM, (long long)CAPE * FF, (long long)FF * DIM,
                (long long)CAPE * DIM, 1, CAPE / BM, DIM / BN,
                (CAPE / BM) * (DIM / BN) * NEXP };
  fused_down<<<gdn.nblk + gw3.nblk, 256, 0, stream>>>(gdn, gw3);

  // combine
  combine_kernel<<<NTOK, 256, 0, stream>>>(SHOUT, EOUT, DEST, GATING, out);
}